// Round 1
// baseline (6384.310 us; speedup 1.0000x reference)
//
#include <hip/hip_runtime.h>
#include <hip/hip_cooperative_groups.h>

namespace cg = cooperative_groups;

#define B_ 32
#define P_ 196
#define D_ 2048
#define A_ 512
#define E_ 512
#define H_ 512
#define V_ 10000
#define L_ 21
#define T_ 20
#define N1 14608            /* 512 att2 + 2048 gate + 2048 ghh + 10000 fc */
#define S1STRIDE (32*14608) /* 467456 */

struct KParams {
  const float* encoder_out; const int* captions; const int* cap_lens;
  const float* enc_att_w; const float* enc_att_b;
  const float* dec_att_w; const float* dec_att_b;
  const float* full_att_w; const float* full_att_b;
  const float* emb;
  const float* init_h_w; const float* init_h_b;
  const float* init_c_w; const float* init_c_b;
  const float* f_beta_w; const float* f_beta_b;
  const float* lstm_w_ih; const float* lstm_w_hh; const float* lstm_b;
  const float* fc_w; const float* fc_b;
  float* out_preds; float* out_caps; float* out_declens; float* out_alphas; float* out_sortind;
  int* sort_ind; int* declen; int* caps_s;
  float* h; float* c; float* mean; float* h0part;
  unsigned short* enc_bf16; unsigned short* waw_bf16; unsigned short* wihE_bf16; unsigned short* embs_bf16;
  float* att1; float* gpre; float* s1out; float* alpha; float* awe; float* gpart;
};

__device__ __forceinline__ unsigned short f2bf(float x){
  unsigned u = __float_as_uint(x);
  unsigned r = ((u >> 16) & 1u) + 0x7FFFu;
  return (unsigned short)((u + r) >> 16);
}
__device__ __forceinline__ unsigned pack2(float a, float b){
  return (unsigned)f2bf(a) | ((unsigned)f2bf(b) << 16);
}
__device__ __forceinline__ float bf2f(unsigned u16){ return __uint_as_float(u16 << 16); }
__device__ __forceinline__ float sigm(float x){ return 1.f/(1.f + __expf(-x)); }
__device__ __forceinline__ float tanh_f(float x){ return 1.f - 2.f/(__expf(2.f*x) + 1.f); }

// ---------------- prologue kernels ----------------

__global__ void k_meta(KParams p){
  __shared__ int len[32], sidx[32], sdecl[32];
  int tid = threadIdx.x;
  if (tid < 32) len[tid] = p.cap_lens[tid];
  __syncthreads();
  if (tid == 0){
    bool used[32];
    for (int i = 0; i < 32; i++) used[i] = false;
    for (int r = 0; r < 32; r++){
      int best = -1, bl = -2;
      for (int i = 0; i < 32; i++) if (!used[i] && len[i] > bl){ bl = len[i]; best = i; }
      used[best] = true; sidx[r] = best; sdecl[r] = bl - 1;
    }
  }
  __syncthreads();
  if (tid < 32){
    p.sort_ind[tid] = sidx[tid]; p.out_sortind[tid] = (float)sidx[tid];
    p.declen[tid]   = sdecl[tid]; p.out_declens[tid] = (float)sdecl[tid];
  }
  for (int idx = tid; idx < B_*L_; idx += 64){
    int b = idx / L_, l = idx - b*L_;
    int cv = p.captions[sidx[b]*L_ + l];
    p.caps_s[idx] = cv; p.out_caps[idx] = (float)cv;
  }
}

__global__ void k_encbf(KParams p){ // sorted encoder -> bf16, 3211264 quads
  int q = blockIdx.x*256 + threadIdx.x;
  const int QB = P_*D_/4; // 100352
  int b = q / QB; int r = q - b*QB;
  float4 v = ((const float4*)(p.encoder_out + (size_t)p.sort_ind[b]*(P_*D_)))[r];
  ((uint2*)p.enc_bf16)[q] = make_uint2(pack2(v.x, v.y), pack2(v.z, v.w));
}

__global__ void k_wbf(KParams p){ // enc_att_w and lstm_w_ih[:512] -> bf16
  int q = blockIdx.x*256 + threadIdx.x; // 524288 quads
  const float4* src; uint2* dst; int qq;
  if (q < 262144){ src = (const float4*)p.enc_att_w; dst = (uint2*)p.waw_bf16;  qq = q; }
  else           { src = (const float4*)p.lstm_w_ih; dst = (uint2*)p.wihE_bf16; qq = q - 262144; }
  float4 v = src[qq];
  dst[qq] = make_uint2(pack2(v.x, v.y), pack2(v.z, v.w));
}

__global__ void k_mean(KParams p){ // mean over P of sorted enc (bf16 src)
  int idx = blockIdx.x*256 + threadIdx.x; // 32768
  int b = idx >> 10, d2 = idx & 1023;
  const unsigned short* e = p.enc_bf16 + (size_t)b*P_*D_ + d2*2;
  float s0 = 0.f, s1 = 0.f;
  for (int pp = 0; pp < P_; ++pp){
    unsigned u = *(const unsigned*)(e + (size_t)pp*D_);
    s0 += bf2f(u & 0xffffu); s1 += bf2f(u >> 16);
  }
  const float inv = 1.f/196.f;
  p.mean[b*D_ + d2*2]     = s0*inv;
  p.mean[b*D_ + d2*2 + 1] = s1*inv;
}

__global__ void k_h0c0(KParams p){ // partial GEMM mean @ [init_h_w | init_c_w]
  __shared__ float mlds[32*128];
  int tid = threadIdx.x;
  int tile = blockIdx.x & 3, kp = blockIdx.x >> 2;
  int k0 = kp*128;
  {
    int tb = tid >> 3, ti = tid & 7;
    const float4* src = (const float4*)(p.mean + tb*D_ + k0);
    float4* dst = (float4*)(mlds + tb*128);
    #pragma unroll
    for (int i = 0; i < 4; i++) dst[ti + 8*i] = src[ti + 8*i];
  }
  __syncthreads();
  int col = tile*256 + tid; // 0..1023
  const float* wb = (col < 512 ? p.init_h_w + col : p.init_c_w + (col - 512)) + (size_t)k0*H_;
  float acc[32];
  #pragma unroll
  for (int i = 0; i < 32; i++) acc[i] = 0.f;
  for (int k = 0; k < 128; k += 4){
    float w0 = wb[0], w1 = wb[H_], w2 = wb[2*H_], w3 = wb[3*H_];
    wb += 4*H_;
    #pragma unroll
    for (int i = 0; i < 32; i++){
      float4 hv = *(const float4*)(mlds + i*128 + k);
      acc[i] += hv.x*w0 + hv.y*w1 + hv.z*w2 + hv.w*w3;
    }
  }
  float* op = p.h0part + (size_t)kp*32768 + col;
  #pragma unroll
  for (int i = 0; i < 32; i++) op[i*1024] = acc[i];
}

__global__ void k_h0c0red(KParams p){
  int idx = blockIdx.x*256 + threadIdx.x; // 32768
  int b = idx >> 10, col = idx & 1023;
  float s = 0.f;
  #pragma unroll
  for (int kp = 0; kp < 16; kp++) s += p.h0part[(size_t)kp*32768 + b*1024 + col];
  if (col < 512) p.h[b*512 + col]       = s + p.init_h_b[col];
  else           p.c[b*512 + col - 512] = s + p.init_c_b[col - 512];
}

__global__ void k_embs(KParams p){ // gather emb rows per (t,b) -> bf16
  int q = blockIdx.x*256 + threadIdx.x; // 81920 quads
  int row = q >> 7, qi = q & 127;
  int t = row >> 5, b = row & 31;
  int cap = p.caps_s[b*L_ + t];
  float4 v = ((const float4*)(p.emb + (size_t)cap*E_))[qi];
  ((uint2*)p.embs_bf16)[q] = make_uint2(pack2(v.x, v.y), pack2(v.z, v.w));
}

// ---------------- generic bf16 MFMA GEMM (128x128 tile) ----------------
using bf16x8 = __attribute__((ext_vector_type(8))) short;
using f32x4  = __attribute__((ext_vector_type(4))) float;

__global__ void __launch_bounds__(256) k_gemm_bf16(const unsigned short* Aq, const unsigned short* Bq,
                                                   const float* bias, float* C, int M, int N, int K){
  __shared__ unsigned short a_lds[128][40];
  __shared__ unsigned short b_lds[128][40];
  int ntiles = N >> 7;
  int bm = (blockIdx.x / ntiles) << 7;
  int bn = (blockIdx.x % ntiles) << 7;
  int tid = threadIdx.x;
  int wave = tid >> 6, lane = tid & 63;
  int wr = (wave >> 1) << 6, wc = (wave & 1) << 6;
  int la = lane & 15, lq = lane >> 4;
  f32x4 acc[4][4] = {};
  for (int k0 = 0; k0 < K; k0 += 32){
    { // stage A tile [128 x 32]
      int r = tid >> 1, ch = (tid & 1) << 4;
      const uint4* asrc = (const uint4*)(Aq + (size_t)(bm + r)*K + k0 + ch);
      uint4 v0 = asrc[0], v1 = asrc[1];
      *(uint4*)&a_lds[r][ch]     = v0;
      *(uint4*)&a_lds[r][ch + 8] = v1;
      // stage B tile transposed -> b_lds[n][k]
      int kk = tid >> 3, n0 = (tid & 7) << 4;
      const unsigned short* bs = Bq + (size_t)(k0 + kk)*N + bn + n0;
      uint4 bv0 = *(const uint4*)bs, bv1 = *(const uint4*)(bs + 8);
      unsigned vals[8] = {bv0.x, bv0.y, bv0.z, bv0.w, bv1.x, bv1.y, bv1.z, bv1.w};
      #pragma unroll
      for (int i = 0; i < 8; i++){
        b_lds[n0 + 2*i][kk]     = (unsigned short)(vals[i] & 0xffffu);
        b_lds[n0 + 2*i + 1][kk] = (unsigned short)(vals[i] >> 16);
      }
    }
    __syncthreads();
    bf16x8 af[4], bfr[4];
    #pragma unroll
    for (int mt = 0; mt < 4; mt++) af[mt]  = *(const bf16x8*)&a_lds[wr + mt*16 + la][lq*8];
    #pragma unroll
    for (int nt = 0; nt < 4; nt++) bfr[nt] = *(const bf16x8*)&b_lds[wc + nt*16 + la][lq*8];
    #pragma unroll
    for (int mt = 0; mt < 4; mt++)
      #pragma unroll
      for (int nt = 0; nt < 4; nt++)
        acc[mt][nt] = __builtin_amdgcn_mfma_f32_16x16x32_bf16(af[mt], bfr[nt], acc[mt][nt], 0, 0, 0);
    __syncthreads();
  }
  #pragma unroll
  for (int mt = 0; mt < 4; mt++){
    int row0 = bm + wr + mt*16 + lq*4;
    #pragma unroll
    for (int nt = 0; nt < 4; nt++){
      int coln = bn + wc + nt*16 + la;
      float bb = bias ? bias[coln] : 0.f;
      #pragma unroll
      for (int r = 0; r < 4; r++)
        C[(size_t)(row0 + r)*N + coln] = acc[mt][nt][r] + bb;
    }
  }
}

// ---------------- cooperative scan kernel ----------------

__global__ void __launch_bounds__(256) k_loop(KParams p){
  cg::grid_group gg = cg::this_grid();
  const int tid = threadIdx.x, blk = blockIdx.x;
  const int lane = tid & 63, wv = tid >> 6;
  __shared__ float shf[4608];

  for (int t = 0; t <= T_; ++t){
    // ===== S1: h @ [dec_att_w | f_beta_w | lstm_w_hh | fc_w], K-split 2 =====
    {
      int nunits = (t == 0) ? 72 : (t == T_) ? 160 : 232;
      if (blk < nunits){
        int tile, bh, kh;
        if (t == 0)      { tile = blk % 18;      bh = (blk/18) & 1; kh = blk/36;  }
        else if (t == T_){ tile = 18 + blk % 40; bh = (blk/40) & 1; kh = blk/80;  }
        else             { tile = blk % 58;      bh = (blk/58) & 1; kh = blk/116; }
        {
          int rb = tid >> 4, rt = tid & 15;
          const float4* src = (const float4*)(p.h + (bh*16 + rb)*H_ + kh*256);
          float4* dst = (float4*)(shf + rb*256);
          #pragma unroll
          for (int i = 0; i < 4; i++) dst[rt + 16*i] = src[rt + 16*i];
        }
        __syncthreads();
        int c = tile*256 + tid;
        int cc = c < N1 ? c : N1 - 1;
        const float* wbase; int wstr;
        if (cc < 512)      { wbase = p.dec_att_w + cc;          wstr = 512;   }
        else if (cc < 2560){ wbase = p.f_beta_w + (cc - 512);   wstr = 2048;  }
        else if (cc < 4608){ wbase = p.lstm_w_hh + (cc - 2560); wstr = 2048;  }
        else               { wbase = p.fc_w + (cc - 4608);      wstr = 10000; }
        wbase += (size_t)(kh*256)*wstr;
        float acc[16];
        #pragma unroll
        for (int i = 0; i < 16; i++) acc[i] = 0.f;
        for (int k = 0; k < 256; k += 4){
          float w0 = wbase[0], w1 = wbase[wstr], w2 = wbase[2*wstr], w3 = wbase[3*wstr];
          wbase += 4*wstr;
          #pragma unroll
          for (int i = 0; i < 16; i++){
            float4 hv = *(const float4*)(shf + i*256 + k);
            acc[i] += hv.x*w0 + hv.y*w1 + hv.z*w2 + hv.w*w3;
          }
        }
        if (c < N1){
          float* op = p.s1out + (size_t)kh*S1STRIDE + (size_t)(bh*16)*N1 + c;
          #pragma unroll
          for (int i = 0; i < 16; i++) op[(size_t)i*N1] = acc[i];
        }
      }
    }
    gg.sync();
    // ===== S2: e + softmax (blocks 0..31) | preds(t-1) reduce (blocks 32..255) =====
    {
      if (blk < 32 && t < T_){
        int b = blk;
        float* att2 = shf; float* fw = shf + 512; float* e = shf + 1024; float* red = shf + 1232;
        for (int ccc = tid; ccc < 512; ccc += 256){
          att2[ccc] = p.s1out[(size_t)b*N1 + ccc] + p.s1out[(size_t)S1STRIDE + (size_t)b*N1 + ccc] + p.dec_att_b[ccc];
          fw[ccc] = p.full_att_w[ccc];
        }
        __syncthreads();
        float4 a2a = *(const float4*)(att2 + lane*8), a2b = *(const float4*)(att2 + lane*8 + 4);
        float4 fwa = *(const float4*)(fw + lane*8),   fwb = *(const float4*)(fw + lane*8 + 4);
        for (int pp = wv; pp < P_; pp += 4){
          const float4* ar = (const float4*)(p.att1 + ((size_t)b*P_ + pp)*A_ + lane*8);
          float4 x0 = ar[0], x1 = ar[1];
          float s = fmaxf(x0.x + a2a.x, 0.f)*fwa.x + fmaxf(x0.y + a2a.y, 0.f)*fwa.y
                  + fmaxf(x0.z + a2a.z, 0.f)*fwa.z + fmaxf(x0.w + a2a.w, 0.f)*fwa.w
                  + fmaxf(x1.x + a2b.x, 0.f)*fwb.x + fmaxf(x1.y + a2b.y, 0.f)*fwb.y
                  + fmaxf(x1.z + a2b.z, 0.f)*fwb.z + fmaxf(x1.w + a2b.w, 0.f)*fwb.w;
          #pragma unroll
          for (int off = 32; off; off >>= 1) s += __shfl_xor(s, off);
          if (lane == 0) e[pp] = s;
        }
        __syncthreads();
        float v = (tid < P_) ? e[tid] : -1e30f;
        #pragma unroll
        for (int off = 32; off; off >>= 1) v = fmaxf(v, __shfl_xor(v, off));
        if (lane == 0) red[wv] = v;
        __syncthreads();
        float m = fmaxf(fmaxf(red[0], red[1]), fmaxf(red[2], red[3]));
        float ex = (tid < P_) ? __expf(e[tid] - m) : 0.f;
        float sv = ex;
        #pragma unroll
        for (int off = 32; off; off >>= 1) sv += __shfl_xor(sv, off);
        if (lane == 0) red[4 + wv] = sv;
        __syncthreads();
        float ssum = red[4] + red[5] + red[6] + red[7];
        if (tid < P_){
          float a = ex/ssum;
          p.alpha[b*P_ + tid] = a;
          bool act = t < p.declen[b];
          p.out_alphas[((size_t)b*T_ + t)*P_ + tid] = act ? a : 0.f;
        }
      } else if (blk >= 32 && t >= 1){
        int tm1 = t - 1;
        for (int idx = (blk - 32)*256 + tid; idx < B_*V_; idx += 224*256){
          int b = idx / V_, vvv = idx - b*V_;
          float val = p.s1out[(size_t)b*N1 + 4608 + vvv]
                    + p.s1out[(size_t)S1STRIDE + (size_t)b*N1 + 4608 + vvv] + p.fc_b[vvv];
          bool act = tm1 < p.declen[b];
          p.out_preds[((size_t)b*T_ + tm1)*V_ + vvv] = act ? val : 0.f;
        }
      }
    }
    gg.sync();
    if (t == T_) break;
    // ===== S3: awe = (alpha @ enc) * sigmoid(gate) =====
    {
      if (blk < 64){
        int b = blk >> 1, dh = blk & 1;
        if (tid < P_) shf[tid] = p.alpha[b*P_ + tid];
        __syncthreads();
        int d0 = (dh*256 + tid)*4;
        const unsigned short* eb = p.enc_bf16 + (size_t)b*P_*D_ + d0;
        float a0 = 0.f, a1 = 0.f, a2 = 0.f, a3 = 0.f;
        for (int pp = 0; pp < P_; ++pp){
          uint2 u = *(const uint2*)(eb + (size_t)pp*D_);
          float al = shf[pp];
          a0 += al*bf2f(u.x & 0xffffu);
          a1 += al*bf2f(u.x >> 16);
          a2 += al*bf2f(u.y & 0xffffu);
          a3 += al*bf2f(u.y >> 16);
        }
        float4 q1 = *(const float4*)(p.s1out + (size_t)b*N1 + 512 + d0);
        float4 q2 = *(const float4*)(p.s1out + (size_t)S1STRIDE + (size_t)b*N1 + 512 + d0);
        float4 qb = *(const float4*)(p.f_beta_b + d0);
        float4 r;
        r.x = a0*sigm(q1.x + q2.x + qb.x);
        r.y = a1*sigm(q1.y + q2.y + qb.y);
        r.z = a2*sigm(q1.z + q2.z + qb.z);
        r.w = a3*sigm(q1.w + q2.w + qb.w);
        *(float4*)(p.awe + (size_t)b*D_ + d0) = r;
      }
    }
    gg.sync();
    // ===== S4: awe @ lstm_w_ih[E:], K-split 16 =====
    {
      int tile = blk & 7, bh = (blk >> 3) & 1, kp = blk >> 4;
      int k0 = kp*128;
      {
        int rb = tid >> 4, rt = tid & 15;
        const float4* src = (const float4*)(p.awe + (size_t)(bh*16 + rb)*D_ + k0);
        float4* dst = (float4*)(shf + rb*128);
        dst[rt] = src[rt]; dst[rt + 16] = src[rt + 16];
      }
      __syncthreads();
      int c = tile*256 + tid;
      const float* wb = p.lstm_w_ih + (size_t)(E_ + k0)*2048 + c;
      float acc[16];
      #pragma unroll
      for (int i = 0; i < 16; i++) acc[i] = 0.f;
      for (int k = 0; k < 128; k += 4){
        float w0 = wb[0], w1 = wb[2048], w2 = wb[4096], w3 = wb[6144];
        wb += 8192;
        #pragma unroll
        for (int i = 0; i < 16; i++){
          float4 hv = *(const float4*)(shf + i*128 + k);
          acc[i] += hv.x*w0 + hv.y*w1 + hv.z*w2 + hv.w*w3;
        }
      }
      float* op = p.gpart + (size_t)kp*(32*2048) + (size_t)(bh*16)*2048 + c;
      #pragma unroll
      for (int i = 0; i < 16; i++) op[i*2048] = acc[i];
    }
    gg.sync();
    // ===== S5: reduce partials + LSTM cell =====
    {
      if (blk < 64){
        int b = blk >> 1, j = (blk & 1)*256 + tid;
        float g[4];
        #pragma unroll
        for (int q = 0; q < 4; q++){
          int col = q*512 + j;
          float s = p.gpre[((size_t)t*32 + b)*2048 + col]
                  + p.s1out[(size_t)b*N1 + 2560 + col]
                  + p.s1out[(size_t)S1STRIDE + (size_t)b*N1 + 2560 + col];
          #pragma unroll
          for (int kp = 0; kp < 16; kp++) s += p.gpart[(size_t)kp*(32*2048) + b*2048 + col];
          g[q] = s;
        }
        float cn = sigm(g[1])*p.c[b*512 + j] + sigm(g[0])*tanh_f(g[2]);
        float hn = sigm(g[3])*tanh_f(cn);
        if (t < p.declen[b]){
          p.c[b*512 + j] = cn;
          p.h[b*512 + j] = hn;
        }
      }
    }
    gg.sync();
  }
}

// ---------------- host launcher ----------------

extern "C" void kernel_launch(void* const* d_in, const int* in_sizes, int n_in,
                              void* d_out, int out_size, void* d_ws, size_t ws_size,
                              hipStream_t stream){
  (void)in_sizes; (void)n_in; (void)out_size; (void)ws_size;
  KParams p;
  p.encoder_out = (const float*)d_in[0];
  p.captions    = (const int*)d_in[1];
  p.cap_lens    = (const int*)d_in[2];
  p.enc_att_w   = (const float*)d_in[3];  p.enc_att_b = (const float*)d_in[4];
  p.dec_att_w   = (const float*)d_in[5];  p.dec_att_b = (const float*)d_in[6];
  p.full_att_w  = (const float*)d_in[7];  p.full_att_b = (const float*)d_in[8];
  p.emb         = (const float*)d_in[9];
  p.init_h_w    = (const float*)d_in[10]; p.init_h_b = (const float*)d_in[11];
  p.init_c_w    = (const float*)d_in[12]; p.init_c_b = (const float*)d_in[13];
  p.f_beta_w    = (const float*)d_in[14]; p.f_beta_b = (const float*)d_in[15];
  p.lstm_w_ih   = (const float*)d_in[16]; p.lstm_w_hh = (const float*)d_in[17]; p.lstm_b = (const float*)d_in[18];
  p.fc_w        = (const float*)d_in[19]; p.fc_b = (const float*)d_in[20];

  float* out = (float*)d_out;
  p.out_preds   = out;                       // 6,400,000
  p.out_caps    = out + 6400000;             // 672
  p.out_declens = out + 6400672;             // 32
  p.out_alphas  = out + 6400704;             // 125,440
  p.out_sortind = out + 6526144;             // 32

  char* w = (char*)d_ws; size_t off = 0;
  auto alloc = [&](size_t bytes)->char*{ char* r = w + off; off = (off + bytes + 255) & ~(size_t)255; return r; };
  p.sort_ind  = (int*)alloc(128);
  p.declen    = (int*)alloc(128);
  p.caps_s    = (int*)alloc(2688);
  p.h         = (float*)alloc(65536);
  p.c         = (float*)alloc(65536);
  p.mean      = (float*)alloc(262144);
  p.enc_bf16  = (unsigned short*)alloc(25690112);
  p.waw_bf16  = (unsigned short*)alloc(2097152);
  p.wihE_bf16 = (unsigned short*)alloc(2097152);
  p.embs_bf16 = (unsigned short*)alloc(655360);
  p.att1      = (float*)alloc(12845056);
  p.gpre      = (float*)alloc(5242880);
  p.s1out     = (float*)alloc(3739648);
  p.alpha     = (float*)alloc(25344);
  p.awe       = (float*)alloc(262144);
  p.gpart     = (float*)alloc(4194304);
  p.h0part    = p.gpart; // aliased: prologue-only vs loop-only

  hipLaunchKernelGGL(k_meta,    dim3(1),     dim3(64),  0, stream, p);
  hipLaunchKernelGGL(k_encbf,   dim3(12544), dim3(256), 0, stream, p);
  hipLaunchKernelGGL(k_wbf,     dim3(2048),  dim3(256), 0, stream, p);
  hipLaunchKernelGGL(k_mean,    dim3(128),   dim3(256), 0, stream, p);
  hipLaunchKernelGGL(k_h0c0,    dim3(64),    dim3(256), 0, stream, p);
  hipLaunchKernelGGL(k_h0c0red, dim3(128),   dim3(256), 0, stream, p);
  hipLaunchKernelGGL(k_embs,    dim3(320),   dim3(256), 0, stream, p);
  hipLaunchKernelGGL(k_gemm_bf16, dim3(80),  dim3(256), 0, stream,
                     (const unsigned short*)p.embs_bf16, (const unsigned short*)p.wihE_bf16,
                     p.lstm_b, p.gpre, 640, 2048, 512);
  hipLaunchKernelGGL(k_gemm_bf16, dim3(196), dim3(256), 0, stream,
                     (const unsigned short*)p.enc_bf16, (const unsigned short*)p.waw_bf16,
                     p.enc_att_b, p.att1, 6272, 512, 2048);

  void* args[] = { (void*)&p };
  hipLaunchCooperativeKernel((void*)k_loop, dim3(256), dim3(256), args, 0, stream);
}